// Round 1
// baseline (1870.458 us; speedup 1.0000x reference)
//
#include <hip/hip_runtime.h>
#include <hip/hip_bf16.h>

// Problem constants (from setup_inputs)
#define BATCH 16
#define D_IN  1024
#define T_LEN 2048
#define K_CB  4096
#define D_CB  256

// d_out layout (float32, concatenated in return order)
#define ZI_OFF 0
#define ZQ_OFF (BATCH * D_CB * T_LEN)                 // 8388608
#define ZO_OFF (ZQ_OFF + BATCH * D_CB * T_LEN)       // 16777216
#define IDX_OFF (ZO_OFF + BATCH * D_IN * T_LEN)      // 50331648

// ---------------- block reduce (256 threads) ----------------
__device__ __forceinline__ float block_sum256(float v) {
    __shared__ float sred[4];
    #pragma unroll
    for (int off = 32; off > 0; off >>= 1) v += __shfl_down(v, off, 64);
    if ((threadIdx.x & 63) == 0) sred[threadIdx.x >> 6] = v;
    __syncthreads();
    float r = sred[0] + sred[1] + sred[2] + sred[3];
    __syncthreads();
    return r;
}

// ---------------- weight norm: W[row] = g[row] * v[row] / ||v[row]|| ----------------
__global__ __launch_bounds__(256) void wn_rows(const float* __restrict__ v,
                                               const float* __restrict__ g,
                                               float* __restrict__ W, int N) {
    int row = blockIdx.x;
    const float* src = v + (size_t)row * N;
    float ss = 0.f;
    for (int c = threadIdx.x; c < N; c += 256) { float x = src[c]; ss += x * x; }
    ss = block_sum256(ss);
    float scale = g[row] * __frsqrt_rn(ss);
    for (int c = threadIdx.x; c < N; c += 256) W[(size_t)row * N + c] = src[c] * scale;
}

// ---------------- codebook: normalize rows, store TRANSPOSED (D_CB x K_CB) ----------------
__global__ __launch_bounds__(256) void cb_norm_t(const float* __restrict__ cb,
                                                 float* __restrict__ cbT) {
    int row = blockIdx.x;            // 0..4095
    int c = threadIdx.x;             // 0..255
    float x = cb[(size_t)row * D_CB + c];
    float ss = block_sum256(x * x);
    float n = sqrtf(ss);
    float scale = 1.0f / fmaxf(n, 1e-12f);
    cbT[(size_t)c * K_CB + row] = x * scale;   // scattered write, one-time 4MB
}

// ---------------- projection GEMM: Out[b,o,t] = sum_c W[o,c]*Z[b,c,t] + bias[o] ----------------
// Tile: 64(o) x 64(t), BK=16, 256 threads, 4x4 microtile.
template <int KDIM, int M>
__global__ __launch_bounds__(256) void proj_gemm(const float* __restrict__ W,
                                                 const float* __restrict__ bias,
                                                 const float* __restrict__ Z,
                                                 float* __restrict__ Out) {
    __shared__ float As[16 * 68];   // [c][o], pad 68 -> 2-way max
    __shared__ float Bs[16 * 64];   // [c][t]
    const int tid = threadIdx.x;
    const int tx = tid & 15, ty = tid >> 4;
    const int t0 = blockIdx.x * 64;
    const int o0 = blockIdx.y * 64;
    const int b  = blockIdx.z;
    const float* Zb = Z + (size_t)b * KDIM * T_LEN;
    float acc[4][4] = {};

    for (int kk = 0; kk < KDIM; kk += 16) {
        {   // stage A (transposed): As[c][o] = W[o0+o][kk+c]
            int c = tid & 15, o = tid >> 4;
            #pragma unroll
            for (int p = 0; p < 4; p++)
                As[c * 68 + o + p * 16] = W[(size_t)(o0 + o + p * 16) * KDIM + kk + c];
            // stage B: Bs[c][t] = Z[b][kk+c][t0+t]
            int t = tid & 63, cz = tid >> 6;
            #pragma unroll
            for (int p = 0; p < 4; p++)
                Bs[(cz + p * 4) * 64 + t] = Zb[(size_t)(kk + cz + p * 4) * T_LEN + t0 + t];
        }
        __syncthreads();
        #pragma unroll
        for (int c = 0; c < 16; c++) {
            float4 a4 = *(const float4*)&As[c * 68 + ty * 4];
            float4 b4 = *(const float4*)&Bs[c * 64 + tx * 4];
            acc[0][0] += a4.x * b4.x; acc[0][1] += a4.x * b4.y; acc[0][2] += a4.x * b4.z; acc[0][3] += a4.x * b4.w;
            acc[1][0] += a4.y * b4.x; acc[1][1] += a4.y * b4.y; acc[1][2] += a4.y * b4.z; acc[1][3] += a4.y * b4.w;
            acc[2][0] += a4.z * b4.x; acc[2][1] += a4.z * b4.y; acc[2][2] += a4.z * b4.z; acc[2][3] += a4.z * b4.w;
            acc[3][0] += a4.w * b4.x; acc[3][1] += a4.w * b4.y; acc[3][2] += a4.w * b4.z; acc[3][3] += a4.w * b4.w;
        }
        __syncthreads();
    }
    #pragma unroll
    for (int i = 0; i < 4; i++) {
        int o = o0 + ty * 4 + i;
        float bv = bias[o];
        float4 r = make_float4(acc[i][0] + bv, acc[i][1] + bv, acc[i][2] + bv, acc[i][3] + bv);
        *(float4*)&Out[((size_t)b * M + o) * T_LEN + t0 + tx * 4] = r;
    }
}

// ---------------- VQ: dist-GEMM + argmax + z_q gather + indices ----------------
// Block: 64 frames (same b, consecutive t). Iterate 64 codeword tiles of 64.
// enc persistent in LDS (64x260 pad); cb chunk staged 32x64 (transposed layout).
__global__ __launch_bounds__(256) void vq_argmax(const float* __restrict__ z_i,
                                                 const float* __restrict__ cbT,
                                                 const float* __restrict__ cb,
                                                 float* __restrict__ z_q,
                                                 float* __restrict__ idx_out) {
    __shared__ float enc_s[64 * 260];  // [f][c], pad 260 -> <=2-way
    __shared__ float cb_s[32 * 64];    // [c][col]; reused as reduction buffer
    __shared__ int   idx_s[64];
    const int tid = threadIdx.x;
    const int f0 = blockIdx.x * 64;
    const int b = f0 >> 11;            // f0 / T_LEN
    const int t0 = f0 & (T_LEN - 1);

    {   // stage enc: enc_s[f][c] = z_i[b,c,t0+f]  (coalesced over f)
        int f = tid & 63, c0 = tid >> 6;
        for (int c = c0; c < D_CB; c += 4)
            enc_s[f * 260 + c] = z_i[((size_t)b * D_CB + c) * T_LEN + t0 + f];
    }
    __syncthreads();

    const int tx = tid & 15, ty = tid >> 4;   // thread owns frames ty*4+i, cols tx*4+j
    float best_val[4];
    int   best_idx[4];
    #pragma unroll
    for (int i = 0; i < 4; i++) { best_val[i] = -3.4e38f; best_idx[i] = 0; }

    for (int kt = 0; kt < 64; kt++) {
        const int k0 = kt * 64;
        float acc[4][4] = {};
        for (int cc = 0; cc < D_CB; cc += 32) {
            {   // stage cb chunk: cb_s[c][col] = cbT[cc+c][k0+col] (coalesced over col)
                int col = tid & 63, c0 = tid >> 6;
                #pragma unroll
                for (int p = 0; p < 8; p++)
                    cb_s[(c0 + p * 4) * 64 + col] = cbT[(size_t)(cc + c0 + p * 4) * K_CB + k0 + col];
            }
            __syncthreads();
            #pragma unroll
            for (int c4 = 0; c4 < 32; c4 += 4) {
                float ea[4][4], cv[4][4];
                #pragma unroll
                for (int i = 0; i < 4; i++) {
                    float4 t = *(const float4*)&enc_s[(ty * 4 + i) * 260 + cc + c4];
                    ea[i][0] = t.x; ea[i][1] = t.y; ea[i][2] = t.z; ea[i][3] = t.w;
                }
                #pragma unroll
                for (int u = 0; u < 4; u++) {
                    float4 t = *(const float4*)&cb_s[(c4 + u) * 64 + tx * 4];
                    cv[u][0] = t.x; cv[u][1] = t.y; cv[u][2] = t.z; cv[u][3] = t.w;
                }
                #pragma unroll
                for (int u = 0; u < 4; u++)
                    #pragma unroll
                    for (int i = 0; i < 4; i++)
                        #pragma unroll
                        for (int j = 0; j < 4; j++)
                            acc[i][j] += ea[i][u] * cv[u][j];
            }
            __syncthreads();
        }
        // running argmax (strict > keeps earliest k on near-ties)
        #pragma unroll
        for (int i = 0; i < 4; i++)
            #pragma unroll
            for (int j = 0; j < 4; j++)
                if (acc[i][j] > best_val[i]) { best_val[i] = acc[i][j]; best_idx[i] = k0 + tx * 4 + j; }
    }

    // cross-tx reduction (overlay onto cb_s; compute reads finished at last sync)
    float* red_val = cb_s;               // 64*16 floats
    int*   red_idx = (int*)(cb_s + 1024);
    #pragma unroll
    for (int i = 0; i < 4; i++) {
        red_val[(ty * 4 + i) * 16 + tx] = best_val[i];
        red_idx[(ty * 4 + i) * 16 + tx] = best_idx[i];
    }
    __syncthreads();
    if (tid < 64) {
        float bv = red_val[tid * 16];
        int   bi = red_idx[tid * 16];
        #pragma unroll
        for (int x = 1; x < 16; x++) {
            float v = red_val[tid * 16 + x];
            if (v > bv) { bv = v; bi = red_idx[tid * 16 + x]; }
        }
        idx_s[tid] = bi;
        idx_out[f0 + tid] = (float)bi;   // indices output as float
    }
    __syncthreads();

    {   // z_q[b,c,t0+f] = codebook[idx_f][c]; writes coalesced over f, reads L2-hot gather
        int f = tid & 63, c0 = tid >> 6;
        int idx = idx_s[f];
        for (int c = c0; c < D_CB; c += 4)
            z_q[((size_t)b * D_CB + c) * T_LEN + t0 + f] = cb[(size_t)idx * D_CB + c];
    }
}

extern "C" void kernel_launch(void* const* d_in, const int* in_sizes, int n_in,
                              void* d_out, int out_size, void* d_ws, size_t ws_size,
                              hipStream_t stream) {
    const float* z     = (const float*)d_in[0];
    const float* in_v  = (const float*)d_in[1];
    const float* in_g  = (const float*)d_in[2];
    const float* in_b  = (const float*)d_in[3];
    const float* out_v = (const float*)d_in[4];
    const float* out_g = (const float*)d_in[5];
    const float* out_b = (const float*)d_in[6];
    const float* cb    = (const float*)d_in[7];

    float* ws    = (float*)d_ws;
    float* W_in  = ws;                       // 256*1024
    float* W_out = ws + 262144;              // 1024*256
    float* cbT   = ws + 524288;              // 256*4096

    float* out  = (float*)d_out;
    float* z_i  = out + ZI_OFF;
    float* z_q  = out + ZQ_OFF;
    float* z_o  = out + ZO_OFF;
    float* idxf = out + IDX_OFF;

    // weight-norm + codebook normalize/transpose
    wn_rows<<<D_CB, 256, 0, stream>>>(in_v, in_g, W_in, D_IN);
    wn_rows<<<D_IN, 256, 0, stream>>>(out_v, out_g, W_out, D_CB);
    cb_norm_t<<<K_CB, 256, 0, stream>>>(cb, cbT);

    // z_i = W_in @ z + in_b
    proj_gemm<D_IN, D_CB><<<dim3(T_LEN / 64, D_CB / 64, BATCH), 256, 0, stream>>>(W_in, in_b, z, z_i);

    // nearest codeword + z_q + indices
    vq_argmax<<<(BATCH * T_LEN) / 64, 256, 0, stream>>>(z_i, cbT, cb, z_q, idxf);

    // z_o = W_out @ z_q + out_b
    proj_gemm<D_CB, D_IN><<<dim3(T_LEN / 64, D_IN / 64, BATCH), 256, 0, stream>>>(W_out, out_b, z_q, z_o);
}

// Round 2
// 1003.947 us; speedup vs baseline: 1.8631x; 1.8631x over previous
//
#include <hip/hip_runtime.h>
#include <hip/hip_bf16.h>

// Problem constants (from setup_inputs)
#define BATCH 16
#define D_IN  1024
#define T_LEN 2048
#define K_CB  4096
#define D_CB  256

// d_out layout (float32, concatenated in return order)
#define ZI_OFF 0
#define ZQ_OFF (BATCH * D_CB * T_LEN)                 // 8388608
#define ZO_OFF (ZQ_OFF + BATCH * D_CB * T_LEN)       // 16777216
#define IDX_OFF (ZO_OFF + BATCH * D_IN * T_LEN)      // 50331648

typedef _Float16 half8 __attribute__((ext_vector_type(8)));
typedef float floatx4 __attribute__((ext_vector_type(4)));

// ---------------- block reduce (256 threads) ----------------
__device__ __forceinline__ float block_sum256(float v) {
    __shared__ float sred[4];
    #pragma unroll
    for (int off = 32; off > 0; off >>= 1) v += __shfl_down(v, off, 64);
    if ((threadIdx.x & 63) == 0) sred[threadIdx.x >> 6] = v;
    __syncthreads();
    float r = sred[0] + sred[1] + sred[2] + sred[3];
    __syncthreads();
    return r;
}

// ---------------- weight norm: W[row] = g[row] * v[row] / ||v[row]|| ----------------
__global__ __launch_bounds__(256) void wn_rows(const float* __restrict__ v,
                                               const float* __restrict__ g,
                                               float* __restrict__ W, int N) {
    int row = blockIdx.x;
    const float* src = v + (size_t)row * N;
    float ss = 0.f;
    for (int c = threadIdx.x; c < N; c += 256) { float x = src[c]; ss += x * x; }
    ss = block_sum256(ss);
    float scale = g[row] * __frsqrt_rn(ss);
    for (int c = threadIdx.x; c < N; c += 256) W[(size_t)row * N + c] = src[c] * scale;
}

// ---------------- codebook: normalize rows + 2-way fp16 split, row-major [cw][k] ----------------
__global__ __launch_bounds__(256) void cb_prep(const float* __restrict__ cb,
                                               _Float16* __restrict__ c1,
                                               _Float16* __restrict__ c2) {
    int row = blockIdx.x;            // 0..4095
    int c = threadIdx.x;             // 0..255
    float x = cb[(size_t)row * D_CB + c];
    float ss = block_sum256(x * x);
    float scale = 1.0f / fmaxf(sqrtf(ss), 1e-12f);
    float v = x * scale;
    _Float16 h1 = (_Float16)v;
    _Float16 h2 = (_Float16)(v - (float)h1);
    c1[(size_t)row * D_CB + c] = h1;
    c2[(size_t)row * D_CB + c] = h2;
}

// ---------------- projection GEMM (fp32): Out[b,o,t] = sum_c W[o,c]*Z[b,c,t] + bias[o] ----------------
template <int KDIM, int M>
__global__ __launch_bounds__(256) void proj_gemm(const float* __restrict__ W,
                                                 const float* __restrict__ bias,
                                                 const float* __restrict__ Z,
                                                 float* __restrict__ Out) {
    __shared__ float As[16 * 68];   // [c][o], pad 68 -> 2-way max
    __shared__ float Bs[16 * 64];   // [c][t]
    const int tid = threadIdx.x;
    const int tx = tid & 15, ty = tid >> 4;
    const int t0 = blockIdx.x * 64;
    const int o0 = blockIdx.y * 64;
    const int b  = blockIdx.z;
    const float* Zb = Z + (size_t)b * KDIM * T_LEN;
    float acc[4][4] = {};

    for (int kk = 0; kk < KDIM; kk += 16) {
        {   // stage A (transposed): As[c][o] = W[o0+o][kk+c]
            int c = tid & 15, o = tid >> 4;
            #pragma unroll
            for (int p = 0; p < 4; p++)
                As[c * 68 + o + p * 16] = W[(size_t)(o0 + o + p * 16) * KDIM + kk + c];
            // stage B: Bs[c][t] = Z[b][kk+c][t0+t]
            int t = tid & 63, cz = tid >> 6;
            #pragma unroll
            for (int p = 0; p < 4; p++)
                Bs[(cz + p * 4) * 64 + t] = Zb[(size_t)(kk + cz + p * 4) * T_LEN + t0 + t];
        }
        __syncthreads();
        #pragma unroll
        for (int c = 0; c < 16; c++) {
            float4 a4 = *(const float4*)&As[c * 68 + ty * 4];
            float4 b4 = *(const float4*)&Bs[c * 64 + tx * 4];
            acc[0][0] += a4.x * b4.x; acc[0][1] += a4.x * b4.y; acc[0][2] += a4.x * b4.z; acc[0][3] += a4.x * b4.w;
            acc[1][0] += a4.y * b4.x; acc[1][1] += a4.y * b4.y; acc[1][2] += a4.y * b4.z; acc[1][3] += a4.y * b4.w;
            acc[2][0] += a4.z * b4.x; acc[2][1] += a4.z * b4.y; acc[2][2] += a4.z * b4.z; acc[2][3] += a4.z * b4.w;
            acc[3][0] += a4.w * b4.x; acc[3][1] += a4.w * b4.y; acc[3][2] += a4.w * b4.z; acc[3][3] += a4.w * b4.w;
        }
        __syncthreads();
    }
    #pragma unroll
    for (int i = 0; i < 4; i++) {
        int o = o0 + ty * 4 + i;
        float bv = bias[o];
        float4 r = make_float4(acc[i][0] + bv, acc[i][1] + bv, acc[i][2] + bv, acc[i][3] + bv);
        *(float4*)&Out[((size_t)b * M + o) * T_LEN + t0 + tx * 4] = r;
    }
}

// ---------------- VQ via f16-split MFMA ----------------
// 32 frames/block (persistent enc splits in LDS), 32 chunks of 128 codewords,
// 4 k-stages of 64 (2 MFMA k-steps each), products e1c1 + e1c2 + e2c1.
// Wave w owns 32 frames x 32 codewords (2 m-tiles x 2 n-tiles of 16x16x32 f16 MFMA).
__global__ __launch_bounds__(256) void vq_mfma(const float* __restrict__ z_i,
                                               const _Float16* __restrict__ cbn1,
                                               const _Float16* __restrict__ cbn2,
                                               const float* __restrict__ cb,
                                               float* __restrict__ z_q,
                                               float* __restrict__ idx_out) {
    __shared__ _Float16 e_s[2][32][264];   // splits x frame x k (pad 264: 2-way max)
    __shared__ _Float16 cb_s[2][128][72];  // splits x cw x k-chunk (pad 72: 2-way max)
    __shared__ float red_v[4][32];
    __shared__ int   red_i[4][32];
    __shared__ int   idx_s[32];

    const int tid  = threadIdx.x;
    const int wv   = tid >> 6;
    const int lane = tid & 63;
    const int lo4  = lane & 15, quad = lane >> 4;
    const int f0 = blockIdx.x * 32;
    const int b  = f0 >> 11;               // f0 / T_LEN
    const int t0 = f0 & (T_LEN - 1);

    // stage enc (fp32) -> 2-way fp16 split, transposed to [f][k]
    for (int i = tid; i < 32 * 256; i += 256) {
        int k = i >> 5, t = i & 31;
        float v = z_i[((size_t)(b * D_CB + k)) * T_LEN + t0 + t];
        _Float16 h1 = (_Float16)v;
        _Float16 h2 = (_Float16)(v - (float)h1);
        e_s[0][t][k] = h1;
        e_s[1][t][k] = h2;
    }

    float best_v[2][4];
    int   best_i[2][4];
    #pragma unroll
    for (int m = 0; m < 2; m++)
        #pragma unroll
        for (int r = 0; r < 4; r++) { best_v[m][r] = -3.4e38f; best_i[m][r] = 0; }

    __syncthreads();

    for (int n = 0; n < 32; n++) {
        const int cwg = n * 128;
        floatx4 acc[2][2];
        #pragma unroll
        for (int m = 0; m < 2; m++)
            #pragma unroll
            for (int t = 0; t < 2; t++) acc[m][t] = (floatx4){0.f, 0.f, 0.f, 0.f};

        // prefetch kc=0 into registers (s 0..3 -> split1, s 4..7 -> split2; no divergence)
        half8 pf[8];
        #pragma unroll
        for (int s = 0; s < 8; s++) {
            int c2 = tid + s * 256;
            const _Float16* src = (s < 4) ? cbn1 : cbn2;
            int rem = c2 & 1023, cw = rem >> 3, ko = (rem & 7) * 8;
            pf[s] = *(const half8*)(src + (size_t)(cwg + cw) * D_CB + ko);
        }

        for (int kc = 0; kc < 4; kc++) {
            // write prefetched tile into LDS (previous compute finished at trailing barrier)
            #pragma unroll
            for (int s = 0; s < 8; s++) {
                int c2 = tid + s * 256;
                int sp = (s < 4) ? 0 : 1;
                int rem = c2 & 1023, cw = rem >> 3, ko = (rem & 7) * 8;
                *(half8*)&cb_s[sp][cw][ko] = pf[s];
            }
            __syncthreads();
            // prefetch next stage while computing this one
            if (kc < 3) {
                #pragma unroll
                for (int s = 0; s < 8; s++) {
                    int c2 = tid + s * 256;
                    const _Float16* src = (s < 4) ? cbn1 : cbn2;
                    int rem = c2 & 1023, cw = rem >> 3, ko = (rem & 7) * 8;
                    pf[s] = *(const half8*)(src + (size_t)(cwg + cw) * D_CB + (kc + 1) * 64 + ko);
                }
            }
            #pragma unroll
            for (int ks = 0; ks < 2; ks++) {
                const int kb = kc * 64 + ks * 32 + quad * 8;  // enc k index
                const int kl = ks * 32 + quad * 8;            // cb tile k index
                half8 a1[2], a2[2], b1[2], b2[2];
                #pragma unroll
                for (int m = 0; m < 2; m++) {
                    a1[m] = *(const half8*)&e_s[0][m * 16 + lo4][kb];
                    a2[m] = *(const half8*)&e_s[1][m * 16 + lo4][kb];
                }
                #pragma unroll
                for (int t = 0; t < 2; t++) {
                    b1[t] = *(const half8*)&cb_s[0][wv * 32 + t * 16 + lo4][kl];
                    b2[t] = *(const half8*)&cb_s[1][wv * 32 + t * 16 + lo4][kl];
                }
                #pragma unroll
                for (int m = 0; m < 2; m++)
                    #pragma unroll
                    for (int t = 0; t < 2; t++) {
                        acc[m][t] = __builtin_amdgcn_mfma_f32_16x16x32_f16(a1[m], b1[t], acc[m][t], 0, 0, 0);
                        acc[m][t] = __builtin_amdgcn_mfma_f32_16x16x32_f16(a1[m], b2[t], acc[m][t], 0, 0, 0);
                        acc[m][t] = __builtin_amdgcn_mfma_f32_16x16x32_f16(a2[m], b1[t], acc[m][t], 0, 0, 0);
                    }
            }
            __syncthreads();
        }

        // fold this chunk's scores into running per-lane argmax
        // C/D layout: col(cw)=lane&15, row(frame)=quad*4+reg
        #pragma unroll
        for (int m = 0; m < 2; m++)
            #pragma unroll
            for (int t = 0; t < 2; t++) {
                int cwi = cwg + wv * 32 + t * 16 + lo4;
                #pragma unroll
                for (int r = 0; r < 4; r++) {
                    float v = acc[m][t][r];
                    if (v > best_v[m][r] || (v == best_v[m][r] && cwi < best_i[m][r])) {
                        best_v[m][r] = v; best_i[m][r] = cwi;
                    }
                }
            }
    }

    // reduce across the 16 column-lanes within each quad
    #pragma unroll
    for (int m = 0; m < 2; m++)
        #pragma unroll
        for (int r = 0; r < 4; r++) {
            float bv = best_v[m][r]; int bi = best_i[m][r];
            #pragma unroll
            for (int off = 8; off > 0; off >>= 1) {
                float ov = __shfl_down(bv, off, 16);
                int   oi = __shfl_down(bi, off, 16);
                if (ov > bv || (ov == bv && oi < bi)) { bv = ov; bi = oi; }
            }
            if (lo4 == 0) {
                red_v[wv][m * 16 + quad * 4 + r] = bv;
                red_i[wv][m * 16 + quad * 4 + r] = bi;
            }
        }
    __syncthreads();
    if (tid < 32) {
        float bv = red_v[0][tid]; int bi = red_i[0][tid];
        #pragma unroll
        for (int w = 1; w < 4; w++) {
            float ov = red_v[w][tid]; int oi = red_i[w][tid];
            if (ov > bv || (ov == bv && oi < bi)) { bv = ov; bi = oi; }
        }
        idx_s[tid] = bi;
        idx_out[f0 + tid] = (float)bi;
    }
    __syncthreads();

    // z_q[b,c,t0+f] = codebook[idx_f][c]
    for (int i = tid; i < 32 * 256; i += 256) {
        int k = i >> 5, t = i & 31;
        z_q[((size_t)(b * D_CB + k)) * T_LEN + t0 + t] = cb[(size_t)idx_s[t] * D_CB + k];
    }
}

extern "C" void kernel_launch(void* const* d_in, const int* in_sizes, int n_in,
                              void* d_out, int out_size, void* d_ws, size_t ws_size,
                              hipStream_t stream) {
    const float* z     = (const float*)d_in[0];
    const float* in_v  = (const float*)d_in[1];
    const float* in_g  = (const float*)d_in[2];
    const float* in_b  = (const float*)d_in[3];
    const float* out_v = (const float*)d_in[4];
    const float* out_g = (const float*)d_in[5];
    const float* out_b = (const float*)d_in[6];
    const float* cb    = (const float*)d_in[7];

    float* ws    = (float*)d_ws;
    float* W_in  = ws;                               // 256*1024 fp32
    float* W_out = ws + 262144;                      // 1024*256 fp32
    _Float16* cbn1 = (_Float16*)(ws + 524288);       // 4096*256 fp16 (2 MB)
    _Float16* cbn2 = (_Float16*)(ws + 1048576);      // 4096*256 fp16 (2 MB)

    float* out  = (float*)d_out;
    float* z_i  = out + ZI_OFF;
    float* z_q  = out + ZQ_OFF;
    float* z_o  = out + ZO_OFF;
    float* idxf = out + IDX_OFF;

    // weight-norm + codebook normalize/split
    wn_rows<<<D_CB, 256, 0, stream>>>(in_v, in_g, W_in, D_IN);
    wn_rows<<<D_IN, 256, 0, stream>>>(out_v, out_g, W_out, D_CB);
    cb_prep<<<K_CB, 256, 0, stream>>>(cb, cbn1, cbn2);

    // z_i = W_in @ z + in_b   (fp32, unchanged from R1)
    proj_gemm<D_IN, D_CB><<<dim3(T_LEN / 64, D_CB / 64, BATCH), 256, 0, stream>>>(W_in, in_b, z, z_i);

    // nearest codeword + z_q + indices (f16-split MFMA)
    vq_mfma<<<(BATCH * T_LEN) / 32, 256, 0, stream>>>(z_i, cbn1, cbn2, cb, z_q, idxf);

    // z_o = W_out @ z_q + out_b   (fp32, unchanged from R1)
    proj_gemm<D_CB, D_IN><<<dim3(T_LEN / 64, D_IN / 64, BATCH), 256, 0, stream>>>(W_out, out_b, z_q, z_o);
}